// Round 2
// baseline (280.234 us; speedup 1.0000x reference)
//
#include <hip/hip_runtime.h>
#include <hip/hip_bf16.h>

// Problem constants
#define NB    4096      // batch rows
#define IND_  512       // feature dim (GEMM K)
#define OUTD_ 512       // output dim (GEMM M, "o")
#define XCOLS 514       // P + IND
#define ND    25        // D^P

// GEMM tiling
#define BM 128          // o-tile
#define BN 128          // b-tile
#define BK 64

typedef float  f32x4  __attribute__((ext_vector_type(4)));
typedef __bf16 bf16x8 __attribute__((ext_vector_type(8)));
typedef unsigned short u16x8 __attribute__((ext_vector_type(8)));

__device__ __forceinline__ unsigned short f2bf(float f) {
  unsigned int x = __float_as_uint(f);
  return (unsigned short)((x + 0x7fffu + ((x >> 16) & 1u)) >> 16);
}

__device__ __forceinline__ float basis_f(float t, int j) {
  switch (j) {
    case 0: return 1.0f;
    case 1: return t;
    case 2: return t * t;
    case 3: { float r = t - 0.33f; r = r > 0.0f ? r : 0.0f; return r * r; }
    default:{ float r = t - 0.66f; r = r > 0.0f ? r : 0.0f; return r * r; }
  }
}

__device__ __forceinline__ void gload_lds16(const void* g, void* l) {
  __builtin_amdgcn_global_load_lds(
      (const __attribute__((address_space(1))) void*)g,
      (__attribute__((address_space(3))) void*)l, 16, 0, 0);
}

// ---------------------------------------------------------------------------
// prep_x: per row b: kb[b][25], XFb[b][i] (bf16), out[b][0:2] = x_treat
// ---------------------------------------------------------------------------
__global__ __launch_bounds__(256) void prep_x_kernel(
    const float* __restrict__ x, unsigned short* __restrict__ XFb,
    float* __restrict__ kb, float* __restrict__ out)
{
  const int b    = blockIdx.x * 4 + (threadIdx.x >> 6);
  const int lane = threadIdx.x & 63;
  const float* xr = x + (size_t)b * XCOLS;

  const float* fp = xr + 2 + lane * 8;
  float2 a0 = *(const float2*)(fp + 0);
  float2 a1 = *(const float2*)(fp + 2);
  float2 a2 = *(const float2*)(fp + 4);
  float2 a3 = *(const float2*)(fp + 6);
  u16x8 pk;
  pk[0] = f2bf(a0.x); pk[1] = f2bf(a0.y); pk[2] = f2bf(a1.x); pk[3] = f2bf(a1.y);
  pk[4] = f2bf(a2.x); pk[5] = f2bf(a2.y); pk[6] = f2bf(a3.x); pk[7] = f2bf(a3.y);
  *reinterpret_cast<u16x8*>(XFb + (size_t)b * IND_ + lane * 8) = pk;

  float t0 = xr[0], t1 = xr[1];
  if (lane < 2) out[(size_t)b * XCOLS + lane] = (lane == 0) ? t0 : t1;
  if (lane < ND) {
    int d1 = lane / 5;
    int d2 = lane - d1 * 5;
    kb[(size_t)b * ND + lane] = basis_f(t0, d1) * basis_f(t1, d2);
  }
}

// ---------------------------------------------------------------------------
// prep_w: W[i,o,d] (fp32) -> Wt[(d*512+o)][i] (bf16), coalesced via LDS tile.
// Block (it, ot): i-tile 64 x o-tile 8. Reads 64 rows x 200 contiguous floats.
// LDS stride 208 words (16B-aligned, transpose-read is lane-consecutive).
// ---------------------------------------------------------------------------
#define PWI 64
#define PWO 8
#define PWC (PWO * ND)   // 200
#define PWP 208          // padded stride (float4-aligned)

__global__ __launch_bounds__(256) void prep_w_kernel(
    const float* __restrict__ W, unsigned short* __restrict__ Wt)
{
  __shared__ float tile[PWI * PWP];   // 53248 B
  const int tid = threadIdx.x;
  const int i0  = blockIdx.x * PWI;
  const int o0  = blockIdx.y * PWO;

  // load: 64 x 50 float4
  for (int idx = tid; idx < PWI * (PWC / 4); idx += 256) {
    int il = idx / (PWC / 4);
    int c4 = idx - il * (PWC / 4);
    float4 v = *(const float4*)(W + ((size_t)(i0 + il) * OUTD_ + o0) * ND + c4 * 4);
    *(float4*)&tile[il * PWP + c4 * 4] = v;
  }
  __syncthreads();

  // transpose-store: thread t < 200 handles (o_l = t/25, d = t%25), col = t
  if (tid < PWC) {
    const int d   = tid % 25;
    const int o_l = tid / 25;
    size_t rowb = ((size_t)d * OUTD_ + o0 + o_l) * (size_t)IND_ + i0;
    #pragma unroll
    for (int j = 0; j < PWI / 8; ++j) {
      u16x8 pk;
      #pragma unroll
      for (int jj = 0; jj < 8; ++jj)
        pk[jj] = f2bf(tile[(j * 8 + jj) * PWP + tid]);
      *reinterpret_cast<u16x8*>(Wt + rowb + j * 8) = pk;
    }
  }
}

// ---------------------------------------------------------------------------
// gemm: D[m=o][n=b] = sum_d kb[b,d] * sum_i Wt_d[o,i]*XFb[b,i]
// 128x128 tile, BK=64, mfma_f32_16x16x32_bf16, global_load_lds width 16,
// XOR-swizzled LDS layout (granule ^= row&7) to kill bank conflicts.
// gridDim.z = S splits of the 25 d-phases; partials to P[z].
// ---------------------------------------------------------------------------
__global__ __launch_bounds__(256, 4) void gemm_kernel(
    const unsigned short* __restrict__ Wt, const unsigned short* __restrict__ XFb,
    const float* __restrict__ kb, float* __restrict__ P)
{
  __shared__ unsigned short Als[BM * BK];   // 16 KB
  __shared__ unsigned short Bls[BN * BK];   // 16 KB

  const int tid  = threadIdx.x;
  const int lane = tid & 63;
  const int w    = tid >> 6;
  const int l15  = lane & 15;
  const int quad = lane >> 4;
  const int o0   = blockIdx.x * BM;
  const int b0   = blockIdx.y * BN;
  const int z    = blockIdx.z;
  const int S    = gridDim.z;
  const int d_start = (z * ND) / S;
  const int d_end   = ((z + 1) * ND) / S;

  const int o_off = (w & 1) * 64;
  const int b_off = (w >> 1) * 64;
  const int srow  = lane >> 3;                   // row within 8-row chunk
  const int sg    = (lane & 7) ^ srow;           // swizzled SOURCE granule
  const int scol  = sg * 8;                      // bf16 col of 16B granule
  const int r7    = l15 & 7;                     // reader row&7

  f32x4 acc[4][4], fin[4][4];
  #pragma unroll
  for (int i = 0; i < 4; ++i)
    #pragma unroll
    for (int j = 0; j < 4; ++j) fin[i][j] = (f32x4)0.0f;

  for (int d = d_start; d < d_end; ++d) {
    // prefetch per-lane kb scales for this phase (L2-hot)
    float kv[4];
    #pragma unroll
    for (int nf = 0; nf < 4; ++nf)
      kv[nf] = kb[(size_t)(b0 + b_off + nf * 16 + l15) * ND + d];

    #pragma unroll
    for (int i = 0; i < 4; ++i)
      #pragma unroll
      for (int j = 0; j < 4; ++j) acc[i][j] = (f32x4)0.0f;

    const size_t arowbase = ((size_t)d * OUTD_ + o0) * (size_t)IND_;

    for (int k0 = 0; k0 < IND_; k0 += BK) {
      #pragma unroll
      for (int c = 0; c < 4; ++c) {
        int chunk = w * 4 + c;
        int r = chunk * 8 + srow;
        const unsigned short* ga = Wt + arowbase + (size_t)r * IND_ + k0 + scol;
        gload_lds16(ga, &Als[chunk * 512]);
        const unsigned short* gb = XFb + (size_t)(b0 + r) * IND_ + k0 + scol;
        gload_lds16(gb, &Bls[chunk * 512]);
      }
      __syncthreads();

      #pragma unroll
      for (int ks = 0; ks < 2; ++ks) {
        bf16x8 af[4], bfr[4];
        #pragma unroll
        for (int mf = 0; mf < 4; ++mf) {
          int row = o_off + mf * 16 + l15;
          int g   = (ks * 4 + quad) ^ r7;
          af[mf] = *reinterpret_cast<const bf16x8*>(&Als[row * BK + g * 8]);
        }
        #pragma unroll
        for (int nf = 0; nf < 4; ++nf) {
          int row = b_off + nf * 16 + l15;
          int g   = (ks * 4 + quad) ^ r7;
          bfr[nf] = *reinterpret_cast<const bf16x8*>(&Bls[row * BK + g * 8]);
        }
        #pragma unroll
        for (int mf = 0; mf < 4; ++mf)
          #pragma unroll
          for (int nf = 0; nf < 4; ++nf)
            acc[mf][nf] = __builtin_amdgcn_mfma_f32_16x16x32_bf16(
                af[mf], bfr[nf], acc[mf][nf], 0, 0, 0);
      }
      __syncthreads();
    }

    // phase end: fin += kb[b,d] * acc ; kb is per-lane (column) constant
    #pragma unroll
    for (int nf = 0; nf < 4; ++nf)
      #pragma unroll
      for (int mf = 0; mf < 4; ++mf)
        #pragma unroll
        for (int r = 0; r < 4; ++r)
          fin[mf][nf][r] += kv[nf] * acc[mf][nf][r];
  }

  float* Pz = P + (size_t)z * NB * OUTD_;
  #pragma unroll
  for (int mf = 0; mf < 4; ++mf)
    #pragma unroll
    for (int nf = 0; nf < 4; ++nf) {
      int bg = b0 + b_off + nf * 16 + l15;
      int og = o0 + o_off + mf * 16 + quad * 4;
      *reinterpret_cast<f32x4*>(&Pz[(size_t)bg * OUTD_ + og]) = fin[mf][nf];
    }
}

// ---------------------------------------------------------------------------
// epilogue: out[b][2+o] = relu(sum_z P[z][b][o] + dot25(kb[b], bias[o]))
// ---------------------------------------------------------------------------
__global__ __launch_bounds__(256) void epilogue_kernel(
    const float* __restrict__ P, const float* __restrict__ kb,
    const float* __restrict__ bias, float* __restrict__ out, int S)
{
  const int idx = blockIdx.x * 256 + threadIdx.x;   // < 4096*512
  const int b = idx >> 9;
  const int o = idx & 511;
  float s = 0.0f;
  for (int zz = 0; zz < S; ++zz) s += P[(size_t)zz * (NB * OUTD_) + idx];
  const float* kr = kb + (size_t)b * ND;
  const float* br = bias + (size_t)o * ND;
  float t = 0.0f;
  #pragma unroll
  for (int d = 0; d < ND; ++d) t += kr[d] * br[d];
  s += t;
  out[(size_t)b * XCOLS + 2 + o] = s > 0.0f ? s : 0.0f;
}

// ---------------------------------------------------------------------------
extern "C" void kernel_launch(void* const* d_in, const int* in_sizes, int n_in,
                              void* d_out, int out_size, void* d_ws, size_t ws_size,
                              hipStream_t stream) {
  const float* x    = (const float*)d_in[0];   // 4096 x 514
  const float* W    = (const float*)d_in[1];   // 512 x 512 x 25
  const float* bias = (const float*)d_in[2];   // 512 x 25
  float* out = (float*)d_out;
  char* ws = (char*)d_ws;

  const size_t xfb_off = 0;                         // 4096*512*2  = 4,194,304
  const size_t wt_off  = 4194304;                   // 12800*512*2 = 13,107,200
  const size_t kb_off  = 17301504;                  // 4096*25*4   = 409,600
  const size_t p_off   = 17711104;                  // S * 8,388,608
  unsigned short* XFb = (unsigned short*)(ws + xfb_off);
  unsigned short* Wt  = (unsigned short*)(ws + wt_off);
  float* kb           = (float*)(ws + kb_off);
  float* P            = (float*)(ws + p_off);

  int S = 4;
  if (ws_size > p_off) {
    size_t avail = (ws_size - p_off) / 8388608ull;
    S = (int)(avail < 1 ? 1 : avail);
    if (S > 8) S = 8;
  } else {
    S = 1;
  }

  prep_x_kernel<<<NB / 4, 256, 0, stream>>>(x, XFb, kb, out);
  prep_w_kernel<<<dim3(IND_ / PWI, OUTD_ / PWO), 256, 0, stream>>>(W, Wt);
  gemm_kernel<<<dim3(OUTD_ / BM, NB / BN, S), 256, 0, stream>>>(Wt, XFb, kb, P);
  epilogue_kernel<<<(NB * OUTD_) / 256, 256, 0, stream>>>(P, kb, bias, out, S);
}

// Round 3
// 185.153 us; speedup vs baseline: 1.5135x; 1.5135x over previous
//
#include <hip/hip_runtime.h>
#include <hip/hip_bf16.h>

// Problem constants
#define NB    4096      // batch rows
#define IND_  512       // feature dim
#define OUTD_ 512       // output dim (GEMM M, "o")
#define XCOLS 514       // P + IND
#define ND    25        // D^P
#define KTOT  12800     // IND_*ND : big-GEMM K

// GEMM tiling
#define BM 128
#define BN 128
#define BK 64

typedef float  f32x4  __attribute__((ext_vector_type(4)));
typedef __bf16 bf16x8 __attribute__((ext_vector_type(8)));
typedef unsigned short u16x8 __attribute__((ext_vector_type(8)));

__device__ __forceinline__ unsigned short f2bf(float f) {
  unsigned int x = __float_as_uint(f);
  return (unsigned short)((x + 0x7fffu + ((x >> 16) & 1u)) >> 16);
}

__device__ __forceinline__ float bf2f(unsigned short u) {
  return __uint_as_float(((unsigned int)u) << 16);
}

__device__ __forceinline__ float basis_f(float t, int j) {
  switch (j) {
    case 0: return 1.0f;
    case 1: return t;
    case 2: return t * t;
    case 3: { float r = t - 0.33f; r = r > 0.0f ? r : 0.0f; return r * r; }
    default:{ float r = t - 0.66f; r = r > 0.0f ? r : 0.0f; return r * r; }
  }
}

__device__ __forceinline__ void gload_lds16(const void* g, void* l) {
  __builtin_amdgcn_global_load_lds(
      (const __attribute__((address_space(1))) void*)g,
      (__attribute__((address_space(3))) void*)l, 16, 0, 0);
}

// ---------------------------------------------------------------------------
// prep_x: per row b: kb[b][25], XFb[b][i] (bf16), out[b][0:2] = x_treat
// ---------------------------------------------------------------------------
__global__ __launch_bounds__(256) void prep_x_kernel(
    const float* __restrict__ x, unsigned short* __restrict__ XFb,
    float* __restrict__ kb, float* __restrict__ out)
{
  const int b    = blockIdx.x * 4 + (threadIdx.x >> 6);
  const int lane = threadIdx.x & 63;
  const float* xr = x + (size_t)b * XCOLS;

  const float* fp = xr + 2 + lane * 8;
  float2 a0 = *(const float2*)(fp + 0);
  float2 a1 = *(const float2*)(fp + 2);
  float2 a2 = *(const float2*)(fp + 4);
  float2 a3 = *(const float2*)(fp + 6);
  u16x8 pk;
  pk[0] = f2bf(a0.x); pk[1] = f2bf(a0.y); pk[2] = f2bf(a1.x); pk[3] = f2bf(a1.y);
  pk[4] = f2bf(a2.x); pk[5] = f2bf(a2.y); pk[6] = f2bf(a3.x); pk[7] = f2bf(a3.y);
  *reinterpret_cast<u16x8*>(XFb + (size_t)b * IND_ + lane * 8) = pk;

  float t0 = xr[0], t1 = xr[1];
  if (lane < 2) out[(size_t)b * XCOLS + lane] = (lane == 0) ? t0 : t1;
  if (lane < ND) {
    int d1 = lane / 5;
    int d2 = lane - d1 * 5;
    kb[(size_t)b * ND + lane] = basis_f(t0, d1) * basis_f(t1, d2);
  }
}

// ---------------------------------------------------------------------------
// prep_b: B'[b][d*512+i] = bf16(kb[b,d] * xf[b,i]).  One block per row b.
// ---------------------------------------------------------------------------
__global__ __launch_bounds__(256) void prep_b_kernel(
    const unsigned short* __restrict__ XFb, const float* __restrict__ kb,
    unsigned short* __restrict__ Bp)
{
  const int b   = blockIdx.x;
  const int tid = threadIdx.x;
  for (int g = tid; g < KTOT / 8; g += 256) {      // 1600 granules of 8
    int d  = g >> 6;
    int ig = g & 63;
    u16x8 v = *(const u16x8*)(XFb + (size_t)b * IND_ + ig * 8);
    float s = kb[b * ND + d];
    u16x8 r;
    #pragma unroll
    for (int jj = 0; jj < 8; ++jj) r[jj] = f2bf(bf2f(v[jj]) * s);
    *(u16x8*)(Bp + (size_t)b * KTOT + g * 8) = r;
  }
}

// ---------------------------------------------------------------------------
// prep_w: W[i,o,d] (fp32) -> Wt[o][d*512+i] (bf16), coalesced via LDS tile.
// ---------------------------------------------------------------------------
#define PWI 64
#define PWO 8
#define PWC (PWO * ND)   // 200
#define PWP 208

__global__ __launch_bounds__(256) void prep_w_kernel(
    const float* __restrict__ W, unsigned short* __restrict__ Wt)
{
  __shared__ float tile[PWI * PWP];
  const int tid = threadIdx.x;
  const int i0  = blockIdx.x * PWI;
  const int o0  = blockIdx.y * PWO;

  for (int idx = tid; idx < PWI * (PWC / 4); idx += 256) {
    int il = idx / (PWC / 4);
    int c4 = idx - il * (PWC / 4);
    float4 v = *(const float4*)(W + ((size_t)(i0 + il) * OUTD_ + o0) * ND + c4 * 4);
    *(float4*)&tile[il * PWP + c4 * 4] = v;
  }
  __syncthreads();

  if (tid < PWC) {
    const int d   = tid % 25;
    const int o_l = tid / 25;
    size_t rowb = (size_t)(o0 + o_l) * KTOT + (size_t)d * IND_ + i0;
    #pragma unroll
    for (int j = 0; j < PWI / 8; ++j) {
      u16x8 pk;
      #pragma unroll
      for (int jj = 0; jj < 8; ++jj)
        pk[jj] = f2bf(tile[(j * 8 + jj) * PWP + tid]);
      *reinterpret_cast<u16x8*>(Wt + rowb + j * 8) = pk;
    }
  }
}

// ---------------------------------------------------------------------------
// gemm_big: C[o][b] = sum_k Wt[o][k] * Bp[b][k], K=12800, split-K 4.
// 128x128 tile, BK=64, swizzled LDS (conflict-free), global_load_lds x16.
// XCD-swizzled block mapping: the 4 o-tiles sharing a (b-tile, split) land
// on the same XCD so B' streams from that XCD's L2 once.
// ---------------------------------------------------------------------------
__global__ __launch_bounds__(256, 2) void gemm_big_kernel(
    const unsigned short* __restrict__ Wt, const unsigned short* __restrict__ Bp,
    float* __restrict__ P)
{
  __shared__ unsigned short Als[BM * BK];   // 16 KB
  __shared__ unsigned short Bls[BN * BK];   // 16 KB

  const int tid  = threadIdx.x;
  const int lane = tid & 63;
  const int w    = tid >> 6;
  const int l15  = lane & 15;
  const int quad = lane >> 4;

  // 512 blocks: id%8 = XCD (dispatch round-robin heuristic; perf-only)
  const int id  = blockIdx.x;
  const int xcd = id & 7;
  const int j   = id >> 3;              // [0,64)
  const int bx  = j & 3;                // o-tile
  const int pg  = xcd * 16 + (j >> 2);  // [0,128) : (b-tile, split) pair
  const int by  = pg & 31;
  const int bz  = pg >> 5;              // split [0,4)

  const int o0 = bx * BM;
  const int b0 = by * BN;
  const int kbase = bz * (KTOT / 4);

  const int o_off = (w & 1) * 64;
  const int b_off = (w >> 1) * 64;
  const int srow  = lane >> 3;
  const int scol  = ((lane & 7) ^ srow) * 8;   // swizzled source granule
  const int r7    = l15 & 7;

  f32x4 acc[4][4];
  #pragma unroll
  for (int i = 0; i < 4; ++i)
    #pragma unroll
    for (int jj = 0; jj < 4; ++jj) acc[i][jj] = (f32x4)0.0f;

  for (int k0 = kbase; k0 < kbase + KTOT / 4; k0 += BK) {
    #pragma unroll
    for (int c = 0; c < 4; ++c) {
      int chunk = w * 4 + c;
      int r = chunk * 8 + srow;
      gload_lds16(Wt + (size_t)(o0 + r) * KTOT + k0 + scol, &Als[chunk * 512]);
      gload_lds16(Bp + (size_t)(b0 + r) * KTOT + k0 + scol, &Bls[chunk * 512]);
    }
    __syncthreads();

    #pragma unroll
    for (int ks = 0; ks < 2; ++ks) {
      bf16x8 af[4], bfr[4];
      #pragma unroll
      for (int mf = 0; mf < 4; ++mf) {
        int row = o_off + mf * 16 + l15;
        int g   = (ks * 4 + quad) ^ r7;
        af[mf] = *reinterpret_cast<const bf16x8*>(&Als[row * BK + g * 8]);
      }
      #pragma unroll
      for (int nf = 0; nf < 4; ++nf) {
        int row = b_off + nf * 16 + l15;
        int g   = (ks * 4 + quad) ^ r7;
        bfr[nf] = *reinterpret_cast<const bf16x8*>(&Bls[row * BK + g * 8]);
      }
      #pragma unroll
      for (int mf = 0; mf < 4; ++mf)
        #pragma unroll
        for (int nf = 0; nf < 4; ++nf)
          acc[mf][nf] = __builtin_amdgcn_mfma_f32_16x16x32_bf16(
              af[mf], bfr[nf], acc[mf][nf], 0, 0, 0);
    }
    __syncthreads();
  }

  float* Pz = P + (size_t)bz * NB * OUTD_;
  #pragma unroll
  for (int mf = 0; mf < 4; ++mf)
    #pragma unroll
    for (int nf = 0; nf < 4; ++nf) {
      int bg = b0 + b_off + nf * 16 + l15;
      int og = o0 + o_off + mf * 16 + quad * 4;
      *reinterpret_cast<f32x4*>(&Pz[(size_t)bg * OUTD_ + og]) = acc[mf][nf];
    }
}

// ---------------------------------------------------------------------------
// gemm_phase (fallback, small-ws): round-1 d-phase structure, swizzled LDS,
// launch_bounds(256,2) (NO (256,4): it spilled acc to scratch in round 2).
// ---------------------------------------------------------------------------
__global__ __launch_bounds__(256, 2) void gemm_phase_kernel(
    const unsigned short* __restrict__ Wt, const unsigned short* __restrict__ XFb,
    const float* __restrict__ kb, float* __restrict__ P)
{
  __shared__ unsigned short Als[BM * BK];
  __shared__ unsigned short Bls[BN * BK];

  const int tid  = threadIdx.x;
  const int lane = tid & 63;
  const int w    = tid >> 6;
  const int l15  = lane & 15;
  const int quad = lane >> 4;
  const int o0   = blockIdx.x * BM;
  const int b0   = blockIdx.y * BN;
  const int z    = blockIdx.z;
  const int S    = gridDim.z;
  const int d_start = (z * ND) / S;
  const int d_end   = ((z + 1) * ND) / S;

  const int o_off = (w & 1) * 64;
  const int b_off = (w >> 1) * 64;
  const int srow  = lane >> 3;
  const int scol  = ((lane & 7) ^ srow) * 8;
  const int r7    = l15 & 7;

  f32x4 acc[4][4], fin[4][4];
  #pragma unroll
  for (int i = 0; i < 4; ++i)
    #pragma unroll
    for (int jj = 0; jj < 4; ++jj) fin[i][jj] = (f32x4)0.0f;

  for (int d = d_start; d < d_end; ++d) {
    float kv[4];
    #pragma unroll
    for (int nf = 0; nf < 4; ++nf)
      kv[nf] = kb[(size_t)(b0 + b_off + nf * 16 + l15) * ND + d];

    #pragma unroll
    for (int i = 0; i < 4; ++i)
      #pragma unroll
      for (int jj = 0; jj < 4; ++jj) acc[i][jj] = (f32x4)0.0f;

    for (int k0 = 0; k0 < IND_; k0 += BK) {
      #pragma unroll
      for (int c = 0; c < 4; ++c) {
        int chunk = w * 4 + c;
        int r = chunk * 8 + srow;
        gload_lds16(Wt + (size_t)(o0 + r) * KTOT + (size_t)d * IND_ + k0 + scol,
                    &Als[chunk * 512]);
        gload_lds16(XFb + (size_t)(b0 + r) * IND_ + k0 + scol, &Bls[chunk * 512]);
      }
      __syncthreads();

      #pragma unroll
      for (int ks = 0; ks < 2; ++ks) {
        bf16x8 af[4], bfr[4];
        #pragma unroll
        for (int mf = 0; mf < 4; ++mf) {
          int row = o_off + mf * 16 + l15;
          int g   = (ks * 4 + quad) ^ r7;
          af[mf] = *reinterpret_cast<const bf16x8*>(&Als[row * BK + g * 8]);
        }
        #pragma unroll
        for (int nf = 0; nf < 4; ++nf) {
          int row = b_off + nf * 16 + l15;
          int g   = (ks * 4 + quad) ^ r7;
          bfr[nf] = *reinterpret_cast<const bf16x8*>(&Bls[row * BK + g * 8]);
        }
        #pragma unroll
        for (int mf = 0; mf < 4; ++mf)
          #pragma unroll
          for (int nf = 0; nf < 4; ++nf)
            acc[mf][nf] = __builtin_amdgcn_mfma_f32_16x16x32_bf16(
                af[mf], bfr[nf], acc[mf][nf], 0, 0, 0);
      }
      __syncthreads();
    }

    #pragma unroll
    for (int nf = 0; nf < 4; ++nf)
      #pragma unroll
      for (int mf = 0; mf < 4; ++mf)
        #pragma unroll
        for (int r = 0; r < 4; ++r)
          fin[mf][nf][r] += kv[nf] * acc[mf][nf][r];
  }

  float* Pz = P + (size_t)z * NB * OUTD_;
  #pragma unroll
  for (int mf = 0; mf < 4; ++mf)
    #pragma unroll
    for (int nf = 0; nf < 4; ++nf) {
      int bg = b0 + b_off + nf * 16 + l15;
      int og = o0 + o_off + mf * 16 + quad * 4;
      *reinterpret_cast<f32x4*>(&Pz[(size_t)bg * OUTD_ + og]) = fin[mf][nf];
    }
}

// ---------------------------------------------------------------------------
// epilogue: out[b][2+o] = relu(sum_s P[s][b][o] + dot25(kb[b], bias[o]))
// ---------------------------------------------------------------------------
__global__ __launch_bounds__(256) void epilogue_kernel(
    const float* __restrict__ P, const float* __restrict__ kb,
    const float* __restrict__ bias, float* __restrict__ out, int S)
{
  const int idx = blockIdx.x * 256 + threadIdx.x;
  const int b = idx >> 9;
  const int o = idx & 511;
  float s = 0.0f;
  for (int zz = 0; zz < S; ++zz) s += P[(size_t)zz * (NB * OUTD_) + idx];
  const float* kr = kb + (size_t)b * ND;
  const float* br = bias + (size_t)o * ND;
  float t = 0.0f;
  #pragma unroll
  for (int d = 0; d < ND; ++d) t += kr[d] * br[d];
  s += t;
  out[(size_t)b * XCOLS + 2 + o] = s > 0.0f ? s : 0.0f;
}

// ---------------------------------------------------------------------------
extern "C" void kernel_launch(void* const* d_in, const int* in_sizes, int n_in,
                              void* d_out, int out_size, void* d_ws, size_t ws_size,
                              hipStream_t stream) {
  const float* x    = (const float*)d_in[0];   // 4096 x 514
  const float* W    = (const float*)d_in[1];   // 512 x 512 x 25
  const float* bias = (const float*)d_in[2];   // 512 x 25
  float* out = (float*)d_out;
  char* ws = (char*)d_ws;

  // ws layout (bytes)
  const size_t xfb_off = 0;                      // 4,194,304
  const size_t wt_off  = 4194304;                // 13,107,200
  const size_t kb_off  = 17301504;               // 409,600
  const size_t p_off   = 17711104;               // up to 4 x 8,388,608
  const size_t bp_off  = 51265536;               // 104,857,600
  const size_t total_big = 156123136;

  unsigned short* XFb = (unsigned short*)(ws + xfb_off);
  unsigned short* Wt  = (unsigned short*)(ws + wt_off);
  float* kb           = (float*)(ws + kb_off);
  float* P            = (float*)(ws + p_off);
  unsigned short* Bp  = (unsigned short*)(ws + bp_off);

  prep_x_kernel<<<NB / 4, 256, 0, stream>>>(x, XFb, kb, out);
  prep_w_kernel<<<dim3(IND_ / PWI, OUTD_ / PWO), 256, 0, stream>>>(W, Wt);

  if (ws_size >= total_big) {
    prep_b_kernel<<<NB, 256, 0, stream>>>(XFb, kb, Bp);
    gemm_big_kernel<<<512, 256, 0, stream>>>(Wt, Bp, P);
    epilogue_kernel<<<(NB * OUTD_) / 256, 256, 0, stream>>>(P, kb, bias, out, 4);
  } else {
    int S = 1;
    if (ws_size > p_off) {
      size_t avail = (ws_size - p_off) / 8388608ull;
      S = (int)(avail < 1 ? 1 : avail);
      if (S > 4) S = 4;
    }
    gemm_phase_kernel<<<dim3(OUTD_ / BM, NB / BN, S), 256, 0, stream>>>(Wt, XFb, kb, P);
    epilogue_kernel<<<(NB * OUTD_) / 256, 256, 0, stream>>>(P, kb, bias, out, S);
  }
}